// Round 10
// baseline (80.629 us; speedup 1.0000x reference)
//
#include <hip/hip_runtime.h>
#include <hip/hip_bf16.h>

// SpatialGATAttention — fully fused, v7 (MI355X / gfx950)
// Round-9 changes vs v6 (55.5us, VALU 46% / MFMA 8% / occ 52%):
//  - Factorized leaky-softmax: exp2(leaky(src+dst)) = max(E*F, E'*F') with
//    E=2^src,E'=2^(0.2src) per row (regs) and F=2^dst,F'=2^(0.2dst) per col
//    (LDS, computed in the dot phase). PV inner loop has NO exp2/add.
//  - Quarter-sized V tiles (sm_v 16KB) -> LDS 37.9KB -> 4 blocks/CU capacity.
//  - Cross-chunk staged-load pipeline: next chunk's x loads issued before the
//    barrier, latency hidden under dots+V-MFMA+PV.

#define NB 8
#define NC 64
#define NT 24
#define NN 512
#define LOG2E 1.44269504088896f

typedef float f32x4 __attribute__((ext_vector_type(4)));
typedef short bf16x8 __attribute__((ext_vector_type(8)));
typedef int   i32x4 __attribute__((ext_vector_type(4)));
typedef unsigned int u32;
typedef u32 u32x2 __attribute__((ext_vector_type(2)));

#ifndef __has_builtin
#define __has_builtin(x) 0
#endif

__device__ __forceinline__ float fast_exp2(float x) {
#if __has_builtin(__builtin_amdgcn_exp2f)
    return __builtin_amdgcn_exp2f(x);
#else
    return exp2f(x);
#endif
}

// hardware RNE conversions (memcpy = free register move)
__device__ __forceinline__ u32 pk_bf16(float lo, float hi) {
    __hip_bfloat162 h2 = __float22bfloat162_rn(float2{lo, hi});
    u32 r; __builtin_memcpy(&r, &h2, 4); return r;
}
__device__ __forceinline__ unsigned short f2bfh(float f) {
    __hip_bfloat16 h = __float2bfloat16(f);
    unsigned short r; __builtin_memcpy(&r, &h, 2); return r;
}
__device__ __forceinline__ float bf2f(unsigned short s) {
    union { unsigned int u; float f; } v;
    v.u = ((unsigned int)s) << 16;
    return v.f;
}

// V fragment layout within a QUARTER (u16 index): k2 = n_quarter>>5 (0..3)
#define VT2_IDX(k2,h,qq,dt,dl,e) \
    ((((((k2)*2+(h))*4+(qq))*2+(dt))*16+(dl))*8+(e))

// swizzled x-chunk (u16 index): row n (0..63), col c (0..63); 16B-block XOR
#define XRB64(n,c) (((n)<<6) + (((((c)>>3) ^ ((n)&7))<<3) | ((c)&7)))

// =====================================================================
// grid 768 = (m:192) x (ch:4) XCD-swizzled, block 512 (8 waves).
// Per block: 4 quarters (own quarter first). Per quarter:
//   2 chunks { barrier; regs->LDS; issue next chunk loads; barrier;
//              dst-dots -> F,F' (exp2 here, cheap); V MFMA }
//   barrier; PV over quarter: w = g * max(E*F, E'*F') in A-frag layout,
//   row-sums via ones-MFMA. Epilogue: normalize + LayerNorm + store.
// =====================================================================
__global__ __launch_bounds__(512, 8)
void gat_one(const float* __restrict__ x, const int* __restrict__ gso,
             const float* __restrict__ Wq, const float* __restrict__ Wk,
             const float* __restrict__ Wv, const float* __restrict__ a_src,
             const float* __restrict__ a_dst, const float* __restrict__ gamma,
             const float* __restrict__ beta, float* __restrict__ out)
{
    __shared__ unsigned short sm_x[4096];     //  8 KB: 64n x 64c bf16 swizzled
    __shared__ unsigned short sm_v[8192];     // 16 KB: V fragments, one quarter
    __shared__ unsigned short sm_wvb[4096];   //  8 KB: Wv B-fragments
    __shared__ float sm_sdst[2][2][128];      //  2 KB: F (v=0), F' (v=1)
    __shared__ float sm_ssrc[2][2][128];      //  2 KB: E (v=0), E' (v=1)
    __shared__ float sm_wqa[2][NC];           // 0.5KB
    __shared__ float sm_wka[2][NC];           // 0.5KB

    const int bid  = blockIdx.x;
    // XCD swizzle: the 4 ch-blocks of one m share (bid & 7) -> same XCD L2
    const int m    = (bid >> 5) * 8 + (bid & 7);
    const int ch   = (bid >> 3) & 3;
    const int b    = m / NT;
    const int tt   = m % NT;
    const int tid  = threadIdx.x;
    const int lane = tid & 63;
    const int wid  = tid >> 6;
    const int fr   = lane & 15;
    const int fq   = lane >> 4;

    // ---- folded attention vectors (pre-scaled by log2 e) ----
    if (tid < 128) {
        const int h = tid >> 6, c = tid & 63;
        float aq = 0.f, ak = 0.f;
        #pragma unroll
        for (int d = 0; d < 32; ++d) {
            aq += Wq[(h*32 + d)*NC + c] * a_src[h*32 + d];
            ak += Wk[(h*32 + d)*NC + c] * a_dst[h*32 + d];
        }
        sm_wqa[h][c] = aq * LOG2E;
        sm_wka[h][c] = ak * LOG2E;
    }
    // ---- Wv as bf16 B-fragments ----
    for (int idx = tid; idx < 4096; idx += 512) {
        const int e   = idx & 7;
        const int dl  = (idx >> 3) & 15;
        const int dt4 = (idx >> 7) & 3;
        const int qq  = (idx >> 9) & 3;
        const int ks  = idx >> 11;
        sm_wvb[idx] = f2bfh(Wv[(dt4*16 + dl)*NC + ks*32 + qq*8 + e]);
    }
    // (first chunk's barrier covers visibility of the above)

    // ones-column B fragment (col 0 = 1.0bf16) for MFMA row-sums
    bf16x8 bones;
    {
        union { i32x4 i; bf16x8 h; } cv;
        const int w = (fr == 0) ? 0x3F803F80 : 0;
        cv.i[0] = w; cv.i[1] = w; cv.i[2] = w; cv.i[3] = w;
        bones = cv.h;
    }

    const int ig = ch*128 + wid*16 + fr;          // this lane's softmax row
    const size_t xrow = ((size_t)(b*NC + wid*8)*NT + tt)*NN;  // c-octet base

    // prologue: load chunk 0 (quarter=ch, c=0) into regs
    float vx[8];
    {
        const int ng0 = ch*128;
        #pragma unroll
        for (int e = 0; e < 8; ++e)
            vx[e] = x[xrow + (size_t)e*NT*NN + ng0 + lane];
    }

    float Ei0 = 0.f, Ei0p = 0.f, Ei1 = 0.f, Ei1p = 0.f;
    f32x4 acc[4] = {};
    f32x4 accs0 = {}, accs1 = {};

    for (int t = 0; t < 4; ++t) {
        const int q = (ch + t) & 3;               // own quarter first

        // ======== proj sub-phase: 2 chunks of 64 n ========
        for (int c = 0; c < 2; ++c) {
            __syncthreads();   // prior readers of sm_x/sm_v/sm_sdst done

            // write staged regs -> swizzled LDS
            {
                i32x4 w;
                #pragma unroll
                for (int j = 0; j < 4; ++j)
                    w[j] = (int)pk_bf16(vx[2*j], vx[2*j+1]);
                *reinterpret_cast<i32x4*>(&sm_x[XRB64(lane, wid*8)]) = w;
            }
            // issue next chunk's loads (latency hides under compute below)
            {
                const int s = t*2 + c;
                if (s < 7) {
                    const int qn  = (ch + ((s+1) >> 1)) & 3;
                    const int ng0 = qn*128 + ((s+1) & 1)*64;
                    #pragma unroll
                    for (int e = 0; e < 8; ++e)
                        vx[e] = x[xrow + (size_t)e*NT*NN + ng0 + lane];
                }
            }
            __syncthreads();

            // ---- dst dots -> F = 2^sk, F' = 2^(0.2 sk) (+E for own rows) ----
            {
                const int nloc = tid >> 3;        // 0..63
                const int cp   = tid & 7;         // c-octet
                float sk0=0.f, sk1=0.f, sq0=0.f, sq1=0.f;
                #pragma unroll
                for (int i = 0; i < 8; ++i) {
                    const int cc = cp*8 + i;
                    const float xv = bf2f(sm_x[XRB64(nloc, cc)]);
                    sk0 += xv * sm_wka[0][cc];
                    sk1 += xv * sm_wka[1][cc];
                    sq0 += xv * sm_wqa[0][cc];
                    sq1 += xv * sm_wqa[1][cc];
                }
                sk0 += __shfl_xor(sk0,1); sk0 += __shfl_xor(sk0,2); sk0 += __shfl_xor(sk0,4);
                sk1 += __shfl_xor(sk1,1); sk1 += __shfl_xor(sk1,2); sk1 += __shfl_xor(sk1,4);
                sq0 += __shfl_xor(sq0,1); sq0 += __shfl_xor(sq0,2); sq0 += __shfl_xor(sq0,4);
                sq1 += __shfl_xor(sq1,1); sq1 += __shfl_xor(sq1,2); sq1 += __shfl_xor(sq1,4);
                if (cp == 0) {
                    const int jl = c*64 + nloc;
                    sm_sdst[0][0][jl] = fast_exp2(sk0);
                    sm_sdst[0][1][jl] = fast_exp2(0.2f*sk0);
                    sm_sdst[1][0][jl] = fast_exp2(sk1);
                    sm_sdst[1][1][jl] = fast_exp2(0.2f*sk1);
                    if (t == 0) {
                        sm_ssrc[0][0][jl] = fast_exp2(sq0);
                        sm_ssrc[0][1][jl] = fast_exp2(0.2f*sq0);
                        sm_ssrc[1][0][jl] = fast_exp2(sq1);
                        sm_ssrc[1][1][jl] = fast_exp2(0.2f*sq1);
                    }
                }
            }

            // ---- V projection: wave -> (n-tile = wid>>1, head = wid&1) ----
            {
                const int nt4 = wid >> 1;
                const int h   = wid & 1;
                f32x4 vacc[2] = {};
                #pragma unroll
                for (int ks = 0; ks < 2; ++ks) {
                    const bf16x8 af = *reinterpret_cast<const bf16x8*>(
                        &sm_x[XRB64(nt4*16 + fr, ks*32 + fq*8)]);
                    #pragma unroll
                    for (int dt = 0; dt < 2; ++dt) {
                        const int dt4 = h*2 + dt;
                        const bf16x8 bfv = *reinterpret_cast<const bf16x8*>(
                            &sm_wvb[(((ks*4 + fq)*4 + dt4)*16 + fr)*8]);
                        vacc[dt] = __builtin_amdgcn_mfma_f32_16x16x32_bf16(
                            af, bfv, vacc[dt], 0, 0, 0);
                    }
                }
                const int nh = c*64 + nt4*16 + 4*fq;   // n within quarter
                #pragma unroll
                for (int dt = 0; dt < 2; ++dt) {
                    u32x2 dd;
                    dd[0] = pk_bf16(vacc[dt][0], vacc[dt][1]);
                    dd[1] = pk_bf16(vacc[dt][2], vacc[dt][3]);
                    *reinterpret_cast<u32x2*>(
                        &sm_v[VT2_IDX(nh>>5, h, (nh>>3)&3, dt, fr, nh&7)]) = dd;
                }
            }
        }
        __syncthreads();   // V-quarter + F/F' complete

        if (t == 0) {
            Ei0  = sm_ssrc[0][0][wid*16 + fr];
            Ei0p = sm_ssrc[0][1][wid*16 + fr];
            Ei1  = sm_ssrc[1][0][wid*16 + fr];
            Ei1p = sm_ssrc[1][1][wid*16 + fr];
        }

        // ======== PV sub-phase over this quarter (4 k2 iters) ========
        const int* gbase = &gso[(size_t)ig*NN + q*128 + fq*8];
        for (int k2 = 0; k2 < 4; ++k2) {
            const int j0l = k2*32 + fq*8;
            const i32x4 g0 = *reinterpret_cast<const i32x4*>(gbase + k2*32);
            const i32x4 g1 = *reinterpret_cast<const i32x4*>(gbase + k2*32 + 4);
            const f32x4 Fa0  = *reinterpret_cast<const f32x4*>(&sm_sdst[0][0][j0l]);
            const f32x4 Fb0  = *reinterpret_cast<const f32x4*>(&sm_sdst[0][0][j0l+4]);
            const f32x4 Fpa0 = *reinterpret_cast<const f32x4*>(&sm_sdst[0][1][j0l]);
            const f32x4 Fpb0 = *reinterpret_cast<const f32x4*>(&sm_sdst[0][1][j0l+4]);
            const f32x4 Fa1  = *reinterpret_cast<const f32x4*>(&sm_sdst[1][0][j0l]);
            const f32x4 Fb1  = *reinterpret_cast<const f32x4*>(&sm_sdst[1][0][j0l+4]);
            const f32x4 Fpa1 = *reinterpret_cast<const f32x4*>(&sm_sdst[1][1][j0l]);
            const f32x4 Fpb1 = *reinterpret_cast<const f32x4*>(&sm_sdst[1][1][j0l+4]);

            u32 u0[8], u1[8];
            #pragma unroll
            for (int e = 0; e < 4; ++e) {
                const float w0 = fmaxf(Ei0*Fa0[e], Ei0p*Fpa0[e]);
                const float w1 = fmaxf(Ei1*Fa1[e], Ei1p*Fpa1[e]);
                const bool gb = (g0[e] != 0);
                u0[e] = gb ? __float_as_uint(w0) : 0u;
                u1[e] = gb ? __float_as_uint(w1) : 0u;
            }
            #pragma unroll
            for (int e = 0; e < 4; ++e) {
                const float w0 = fmaxf(Ei0*Fb0[e], Ei0p*Fpb0[e]);
                const float w1 = fmaxf(Ei1*Fb1[e], Ei1p*Fpb1[e]);
                const bool gb = (g1[e] != 0);
                u0[4+e] = gb ? __float_as_uint(w0) : 0u;
                u1[4+e] = gb ? __float_as_uint(w1) : 0u;
            }
            union { i32x4 i; bf16x8 h; } c0, c1;
            c0.i[0] = __builtin_amdgcn_perm(u0[1], u0[0], 0x07060302u);
            c0.i[1] = __builtin_amdgcn_perm(u0[3], u0[2], 0x07060302u);
            c0.i[2] = __builtin_amdgcn_perm(u0[5], u0[4], 0x07060302u);
            c0.i[3] = __builtin_amdgcn_perm(u0[7], u0[6], 0x07060302u);
            c1.i[0] = __builtin_amdgcn_perm(u1[1], u1[0], 0x07060302u);
            c1.i[1] = __builtin_amdgcn_perm(u1[3], u1[2], 0x07060302u);
            c1.i[2] = __builtin_amdgcn_perm(u1[5], u1[4], 0x07060302u);
            c1.i[3] = __builtin_amdgcn_perm(u1[7], u1[6], 0x07060302u);
            const bf16x8 af0 = c0.h, af1 = c1.h;

            accs0 = __builtin_amdgcn_mfma_f32_16x16x32_bf16(af0, bones, accs0, 0,0,0);
            {
                const bf16x8 b0 = *reinterpret_cast<const bf16x8*>(
                    &sm_v[VT2_IDX(k2,0,fq,0,fr,0)]);
                const bf16x8 b1 = *reinterpret_cast<const bf16x8*>(
                    &sm_v[VT2_IDX(k2,0,fq,1,fr,0)]);
                acc[0] = __builtin_amdgcn_mfma_f32_16x16x32_bf16(af0, b0, acc[0], 0,0,0);
                acc[1] = __builtin_amdgcn_mfma_f32_16x16x32_bf16(af0, b1, acc[1], 0,0,0);
            }
            accs1 = __builtin_amdgcn_mfma_f32_16x16x32_bf16(af1, bones, accs1, 0,0,0);
            {
                const bf16x8 b0 = *reinterpret_cast<const bf16x8*>(
                    &sm_v[VT2_IDX(k2,1,fq,0,fr,0)]);
                const bf16x8 b1 = *reinterpret_cast<const bf16x8*>(
                    &sm_v[VT2_IDX(k2,1,fq,1,fr,0)]);
                acc[2] = __builtin_amdgcn_mfma_f32_16x16x32_bf16(af1, b0, acc[2], 0,0,0);
                acc[3] = __builtin_amdgcn_mfma_f32_16x16x32_bf16(af1, b1, acc[3], 0,0,0);
            }
        }
    }

    // ---- epilogue: normalize + LayerNorm + store (B,C,T,N) ----
    float gmv[4], btv[4];
    #pragma unroll
    for (int dt4 = 0; dt4 < 4; ++dt4) {
        gmv[dt4] = gamma[dt4*16 + fr];
        btv[dt4] = beta [dt4*16 + fr];
    }
    #pragma unroll
    for (int rg = 0; rg < 4; ++rg) {
        const int rowloc = 4*fq + rg;
        const float rs0 = __shfl(accs0[rg], lane & 48);
        const float rs1 = __shfl(accs1[rg], lane & 48);
        const float inv0 = 1.f / rs0, inv1 = 1.f / rs1;
        float vv[4];
        vv[0] = acc[0][rg] * inv0;
        vv[1] = acc[1][rg] * inv0;
        vv[2] = acc[2][rg] * inv1;
        vv[3] = acc[3][rg] * inv1;
        float sum = vv[0]+vv[1]+vv[2]+vv[3];
        float ssq = vv[0]*vv[0]+vv[1]*vv[1]+vv[2]*vv[2]+vv[3]*vv[3];
        sum += __shfl_xor(sum,1); sum += __shfl_xor(sum,2);
        sum += __shfl_xor(sum,4); sum += __shfl_xor(sum,8);
        ssq += __shfl_xor(ssq,1); ssq += __shfl_xor(ssq,2);
        ssq += __shfl_xor(ssq,4); ssq += __shfl_xor(ssq,8);
        const float mu   = sum * (1.f/64.f);
        const float var  = ssq * (1.f/64.f) - mu*mu;
        const float rstd = rsqrtf(var + 1e-5f);
        const int irow = ch*128 + wid*16 + rowloc;
        #pragma unroll
        for (int dt4 = 0; dt4 < 4; ++dt4) {
            const float o = (vv[dt4] - mu) * rstd * gmv[dt4] + btv[dt4];
            out[((size_t)(b*NC + dt4*16 + fr)*NT + tt)*NN + irow] = o;
        }
    }
}

extern "C" void kernel_launch(void* const* d_in, const int* in_sizes, int n_in,
                              void* d_out, int out_size, void* d_ws, size_t ws_size,
                              hipStream_t stream) {
    (void)in_sizes; (void)n_in; (void)out_size; (void)d_ws; (void)ws_size;
    const float* x     = (const float*)d_in[0];
    const int*   gso   = (const int*)  d_in[1];
    const float* Wq    = (const float*)d_in[2];
    const float* Wk    = (const float*)d_in[3];
    const float* Wv    = (const float*)d_in[4];
    const float* a_src = (const float*)d_in[5];
    const float* a_dst = (const float*)d_in[6];
    const float* gamma = (const float*)d_in[7];
    const float* beta  = (const float*)d_in[8];
    float* out = (float*)d_out;

    gat_one<<<768, 512, 0, stream>>>(x, gso, Wq, Wk, Wv, a_src, a_dst,
                                     gamma, beta, out);
}

// Round 11
// 50.379 us; speedup vs baseline: 1.6004x; 1.6004x over previous
//
#include <hip/hip_runtime.h>
#include <hip/hip_bf16.h>

// SpatialGATAttention — 2-kernel pipeline + factorized softmax, v8
// (MI355X / gfx950)
// Round-11: revert v7 (spill disaster: launch_bounds(512,8) + staged regs ->
// 140MB scratch traffic). Champion 2-kernel base (R3, 49.3us) + factorized
// leaky-softmax: exp(leaky(src+dst)) = max(E*F, E'*F'), E/E'/F/F' computed
// ONCE per (m,n) in proj (393K exp2) and stored in ws; attn inner loop is
// mul/mul/max/cndmask — no exp2, no mask adds, mask_ws dropped (gso direct).
// attn: launch_bounds(512,6) (proven safe cap), no unroll pragmas.

#define NB 8
#define NC 64
#define NT 24
#define NN 512
#define NM 192
#define LOG2E 1.44269504088896f

typedef float f32x4 __attribute__((ext_vector_type(4)));
typedef short bf16x8 __attribute__((ext_vector_type(8)));
typedef int   i32x4 __attribute__((ext_vector_type(4)));
typedef unsigned int u32;
typedef u32 u32x2 __attribute__((ext_vector_type(2)));

#ifndef __has_builtin
#define __has_builtin(x) 0
#endif

__device__ __forceinline__ float fast_exp2(float x) {
#if __has_builtin(__builtin_amdgcn_exp2f)
    return __builtin_amdgcn_exp2f(x);
#else
    return exp2f(x);
#endif
}

// manual RNE (mono fallback only)
__device__ __forceinline__ unsigned short f2bf(float f) {
    union { float f; unsigned int u; } v; v.f = f;
    unsigned int u = v.u;
    u += 0x7fffu + ((u >> 16) & 1u);
    return (unsigned short)(u >> 16);
}

// hardware RNE conversions (memcpy = free register move)
__device__ __forceinline__ u32 pk_bf16(float lo, float hi) {
    __hip_bfloat162 h2 = __float22bfloat162_rn(float2{lo, hi});
    u32 r; __builtin_memcpy(&r, &h2, 4); return r;
}
__device__ __forceinline__ unsigned short f2bfh(float f) {
    __hip_bfloat16 h = __float2bfloat16(f);
    unsigned short r; __builtin_memcpy(&r, &h, 2); return r;
}
__device__ __forceinline__ float bf2f(unsigned short s) {
    union { unsigned int u; float f; } v;
    v.u = ((unsigned int)s) << 16;
    return v.f;
}

// k-major V fragment layout (u16 index). k2 = j>>5 (0..15 in ws, 0..7 in LDS)
#define VT2_IDX(k2,h,qq,dt,dl,e) \
    ((((((k2)*2+(h))*4+(qq))*2+(dt))*16+(dl))*8+(e))

// swizzled x-tile (u16 index): row n (0..127), col c (0..63); 16B-block XOR
#define XRB(n,c) (((n)<<6) + (((((c)>>3) ^ ((n)&7))<<3) | ((c)&7)))

// old layout for the mono fallback
#define VT_IDX(h,k,qq,dt,dl,e) ((((((h)*16+(k))*4+(qq))*2+(dt))*16+(dl))*8+(e))

// ---- workspace layout (bytes) ----
// vt:   u16 [192][32768]            = 12,582,912
// ssrc: f32 [192][h:2][v:2][512]    =  1,572,864   (E, E')
// sdst: f32 [192][h:2][v:2][512]    =  1,572,864   (F, F')
#define WS_VT_OFF   0u
#define WS_SSRC_OFF 12582912u
#define WS_SDST_OFF 14155776u
#define WS_NEEDED   15728640u

// =====================================================================
// Kernel 1: projection + factorized score vectors
// grid: 768 = (m:192) x (ch:4), block: 512
// =====================================================================
__global__ __launch_bounds__(512)
void gat_proj(const float* __restrict__ x,
              const float* __restrict__ Wq, const float* __restrict__ Wk,
              const float* __restrict__ Wv, const float* __restrict__ a_src,
              const float* __restrict__ a_dst,
              unsigned short* __restrict__ vt_ws, float* __restrict__ ssrc_ws,
              float* __restrict__ sdst_ws)
{
    __shared__ unsigned short sm_xrb[8192];      // swizzled [128][64] bf16, 16KB
    __shared__ unsigned short sm_wvb[4096];
    __shared__ float sm_wqa[2][NC];
    __shared__ float sm_wka[2][NC];

    const int bid  = blockIdx.x;
    const int m    = bid >> 2;
    const int ch   = bid & 3;
    const int b    = m / NT;
    const int tt   = m % NT;
    const int tid  = threadIdx.x;
    const int lane = tid & 63;
    const int wid  = tid >> 6;
    const int fr   = lane & 15;
    const int fq   = lane >> 4;

    // ---- folded attention vectors, pre-scaled by log2(e) ----
    if (tid < 128) {
        const int h = tid >> 6, c = tid & 63;
        float aq = 0.f, ak = 0.f;
        #pragma unroll
        for (int d = 0; d < 32; ++d) {
            aq += Wq[(h*32 + d)*NC + c] * a_src[h*32 + d];
            ak += Wk[(h*32 + d)*NC + c] * a_dst[h*32 + d];
        }
        sm_wqa[h][c] = aq * LOG2E;
        sm_wka[h][c] = ak * LOG2E;
    }
    // ---- Wv as bf16 B-fragments ----
    for (int idx = tid; idx < 4096; idx += 512) {
        const int e   = idx & 7;
        const int dl  = (idx >> 3) & 15;
        const int dt4 = (idx >> 7) & 3;
        const int qq  = (idx >> 9) & 3;
        const int ks  = idx >> 11;
        sm_wvb[idx] = f2bfh(Wv[(dt4*16 + dl)*NC + ks*32 + qq*8 + e]);
    }

    const int nbase = ch * 128;

    // ---- stage x chunk -> swizzled bf16 LDS (coalesced, hw cvt_pk) ----
    {
        const int sl = tid & 127;       // n local
        const int sc = tid >> 7;        // c-quarter
        #pragma unroll
        for (int half = 0; half < 2; ++half) {
            float v[8];
            #pragma unroll
            for (int e = 0; e < 8; ++e) {
                const int c = sc*16 + half*8 + e;
                v[e] = x[((size_t)(b*NC + c)*NT + tt)*NN + nbase + sl];
            }
            i32x4 w;
            #pragma unroll
            for (int j = 0; j < 4; ++j)
                w[j] = (int)pk_bf16(v[2*j], v[2*j+1]);
            *reinterpret_cast<i32x4*>(&sm_xrb[XRB(sl, sc*16 + half*8)]) = w;
        }
    }
    __syncthreads();

    // ---- score vectors -> E,E',F,F' (exp2 HERE, once per (m,n)) ----
    {
        const int nl = tid >> 2;        // 0..127 local n
        const int pp = tid & 3;         // c-quarter
        float sq0=0.f, sq1=0.f, sk0=0.f, sk1=0.f;
        #pragma unroll
        for (int cc = 0; cc < 16; ++cc) {
            const int c = pp*16 + cc;
            const float xv = bf2f(sm_xrb[XRB(nl, c)]);
            sq0 += xv * sm_wqa[0][c];
            sq1 += xv * sm_wqa[1][c];
            sk0 += xv * sm_wka[0][c];
            sk1 += xv * sm_wka[1][c];
        }
        sq0 += __shfl_xor(sq0,1); sq0 += __shfl_xor(sq0,2);
        sq1 += __shfl_xor(sq1,1); sq1 += __shfl_xor(sq1,2);
        sk0 += __shfl_xor(sk0,1); sk0 += __shfl_xor(sk0,2);
        sk1 += __shfl_xor(sk1,1); sk1 += __shfl_xor(sk1,2);
        if (pp == 0) {
            const int n = nbase + nl;
            float* sb = ssrc_ws + (size_t)m*4*NN;
            float* db = sdst_ws + (size_t)m*4*NN;
            sb[0*NN + n] = fast_exp2(sq0);          // h0 E
            sb[1*NN + n] = fast_exp2(0.2f*sq0);     // h0 E'
            sb[2*NN + n] = fast_exp2(sq1);          // h1 E
            sb[3*NN + n] = fast_exp2(0.2f*sq1);     // h1 E'
            db[0*NN + n] = fast_exp2(sk0);          // h0 F
            db[1*NN + n] = fast_exp2(0.2f*sk0);     // h0 F'
            db[2*NN + n] = fast_exp2(sk1);          // h1 F
            db[3*NN + n] = fast_exp2(0.2f*sk1);     // h1 F'
        }
    }

    // ---- V projection MFMA: wave owns n-tile [nbase + wid*16, +16) ----
    {
        f32x4 vacc[4] = {};
        #pragma unroll
        for (int ks = 0; ks < 2; ++ks) {
            const bf16x8 af = *reinterpret_cast<const bf16x8*>(
                &sm_xrb[XRB(wid*16 + fr, ks*32 + fq*8)]);
            #pragma unroll
            for (int dt4 = 0; dt4 < 4; ++dt4) {
                const bf16x8 bfv = *reinterpret_cast<const bf16x8*>(
                    &sm_wvb[(((ks*4 + fq)*4 + dt4)*16 + fr)*8]);
                vacc[dt4] = __builtin_amdgcn_mfma_f32_16x16x32_bf16(
                    af, bfv, vacc[dt4], 0, 0, 0);
            }
        }
        const int n0 = nbase + wid*16 + 4*fq;
        #pragma unroll
        for (int dt4 = 0; dt4 < 4; ++dt4) {
            const int h = dt4 >> 1, dt = dt4 & 1;
            u32x2 dd;
            dd[0] = pk_bf16(vacc[dt4][0], vacc[dt4][1]);
            dd[1] = pk_bf16(vacc[dt4][2], vacc[dt4][3]);
            *reinterpret_cast<u32x2*>(
                &vt_ws[(size_t)m*32768 +
                       VT2_IDX(n0>>5, h, (n0>>3)&3, dt, fr, n0&7)]) = dd;
        }
    }
}

// =====================================================================
// Kernel 2: attention (factorized weights) + PV + LayerNorm
// grid: 768 XCD-swizzled; block 512; V staged in two 32KB j-halves.
// LDS = 32K(V) + 8K(F/F') + 2K(E/E') = 43KB -> 3 blocks/CU.
// =====================================================================
__global__ __launch_bounds__(512, 6)
void gat_attn(const unsigned short* __restrict__ vt_ws,
              const float* __restrict__ ssrc_ws, const float* __restrict__ sdst_ws,
              const int* __restrict__ gso,
              const float* __restrict__ gamma, const float* __restrict__ beta,
              float* __restrict__ out)
{
    __shared__ unsigned short sm_vt[16384];      // 32 KB: one j-half of V
    __shared__ float sm_F[2][2][NN];             //  8 KB: F (v=0), F' (v=1)
    __shared__ float sm_E[2][2][128];            //  2 KB: E, E' for own rows

    const int bid  = blockIdx.x;
    // XCD swizzle: 4 ch-blocks of one m -> same (bid % 8) residue
    const int m    = (bid >> 5) * 8 + (bid & 7);
    const int ch   = (bid >> 3) & 3;
    const int tid  = threadIdx.x;
    const int lane = tid & 63;
    const int wid  = tid >> 6;
    const int fr   = lane & 15;
    const int fq   = lane >> 4;

    // ---- stage V half 0 (async) + F/F' + E/E' ----
    const char* vsrc = (const char*)(vt_ws + (size_t)m * 32768);
#if __has_builtin(__builtin_amdgcn_global_load_lds)
    #pragma unroll
    for (int i = 0; i < 4; ++i) {
        __builtin_amdgcn_global_load_lds(
            (const __attribute__((address_space(1))) void*)
                (vsrc + i*8192 + tid*16),
            (__attribute__((address_space(3))) void*)
                (((__attribute__((address_space(3))) char*)sm_vt) +
                 i*8192 + (tid & ~63)*16),
            16, 0, 0);
    }
#else
    #pragma unroll
    for (int i = 0; i < 4; ++i) {
        reinterpret_cast<i32x4*>(sm_vt)[i*512 + tid] =
            reinterpret_cast<const i32x4*>(vsrc)[i*512 + tid];
    }
#endif
    // F/F' both heads: 2048 f32 = 512 f32x4, one per thread
    reinterpret_cast<f32x4*>(&sm_F[0][0][0])[tid] =
        reinterpret_cast<const f32x4*>(sdst_ws + (size_t)m*4*NN)[tid];
    // E/E' own 128 rows: 512 scalars, one per thread
    {
        const int h = tid >> 8, v = (tid >> 7) & 1, nloc = tid & 127;
        sm_E[h][v][nloc] =
            ssrc_ws[((size_t)m*4 + h*2 + v)*NN + ch*128 + nloc];
    }
    __syncthreads();

    // ones-column B fragment (col 0 = 1.0bf16) for MFMA row-sums
    bf16x8 bones;
    {
        union { i32x4 i; bf16x8 h; } cv;
        const int w = (fr == 0) ? 0x3F803F80 : 0;
        cv.i[0] = w; cv.i[1] = w; cv.i[2] = w; cv.i[3] = w;
        bones = cv.h;
    }

    const int iloc = wid * 16;
    const int ig   = ch*128 + iloc + fr;
    const float Ei0  = sm_E[0][0][iloc + fr];
    const float Ei0p = sm_E[0][1][iloc + fr];
    const float Ei1  = sm_E[1][0][iloc + fr];
    const float Ei1p = sm_E[1][1][iloc + fr];
    const int* grow = gso + (size_t)ig * NN + fq*8;

    f32x4 acc[4] = {};
    f32x4 accs0 = {}, accs1 = {};

    #pragma unroll
    for (int hf = 0; hf < 2; ++hf) {
        for (int k2 = 0; k2 < 8; ++k2) {
            const int k  = hf*8 + k2;
            const int j0 = k*32 + fq*8;
            const i32x4 g0 = *reinterpret_cast<const i32x4*>(grow + k*32);
            const i32x4 g1 = *reinterpret_cast<const i32x4*>(grow + k*32 + 4);

            // ---- head 0: w = g * max(Ei*F, Ei'*F') ----
            {
                const f32x4 Fa = *reinterpret_cast<const f32x4*>(&sm_F[0][0][j0]);
                const f32x4 Fb = *reinterpret_cast<const f32x4*>(&sm_F[0][0][j0+4]);
                const f32x4 Pa = *reinterpret_cast<const f32x4*>(&sm_F[0][1][j0]);
                const f32x4 Pb = *reinterpret_cast<const f32x4*>(&sm_F[0][1][j0+4]);
                u32 u[8];
                #pragma unroll
                for (int e = 0; e < 4; ++e) {
                    const float w = fmaxf(Ei0*Fa[e], Ei0p*Pa[e]);
                    u[e] = (g0[e] != 0) ? __float_as_uint(w) : 0u;
                }
                #pragma unroll
                for (int e = 0; e < 4; ++e) {
                    const float w = fmaxf(Ei0*Fb[e], Ei0p*Pb[e]);
                    u[4+e] = (g1[e] != 0) ? __float_as_uint(w) : 0u;
                }
                union { i32x4 i; bf16x8 h; } cv;
                cv.i[0] = __builtin_amdgcn_perm(u[1], u[0], 0x07060302u);
                cv.i[1] = __builtin_amdgcn_perm(u[3], u[2], 0x07060302u);
                cv.i[2] = __builtin_amdgcn_perm(u[5], u[4], 0x07060302u);
                cv.i[3] = __builtin_amdgcn_perm(u[7], u[6], 0x07060302u);
                const bf16x8 af = cv.h;
                accs0 = __builtin_amdgcn_mfma_f32_16x16x32_bf16(af, bones, accs0, 0,0,0);
                const bf16x8 b0 = *reinterpret_cast<const bf16x8*>(
                    &sm_vt[VT2_IDX(k2,0,fq,0,fr,0)]);
                const bf16x8 b1 = *reinterpret_cast<const bf16x8*>(
                    &sm_vt[VT2_IDX(k2,0,fq,1,fr,0)]);
                acc[0] = __builtin_amdgcn_mfma_f32_16x16x32_bf16(af, b0, acc[0], 0,0,0);
                acc[1] = __builtin_amdgcn_mfma_f32_16x16x32_bf16(af, b1, acc[1], 0,0,0);
            }
            // ---- head 1 ----
            {
                const f32x4 Fa = *reinterpret_cast<const f32x4*>(&sm_F[1][0][j0]);
                const f32x4 Fb = *reinterpret_cast<const f32x4*>(&sm_F[1][0][j0+4]);
                const f32x4 Pa = *reinterpret_cast<const f32x4*>(&sm_F[1][1][j0]);
                const f32x4 Pb = *reinterpret_cast<const f32x4*>(&sm_F[1][1][j0+4]);
                u32 u[8];
                #pragma unroll
                for (int e = 0; e < 4; ++e) {
                    const float w = fmaxf(Ei1*Fa[e], Ei1p*Pa[e]);
                    u[e] = (g0[e] != 0) ? __float_as_uint(w) : 0u;
                }
                #pragma unroll
                for (int e = 0; e < 4; ++e) {
                    const float w = fmaxf(Ei1*Fb[e], Ei1p*Pb[e]);
                    u[4+e] = (g1[e] != 0) ? __float_as_uint(w) : 0u;
                }
                union { i32x4 i; bf16x8 h; } cv;
                cv.i[0] = __builtin_amdgcn_perm(u[1], u[0], 0x07060302u);
                cv.i[1] = __builtin_amdgcn_perm(u[3], u[2], 0x07060302u);
                cv.i[2] = __builtin_amdgcn_perm(u[5], u[4], 0x07060302u);
                cv.i[3] = __builtin_amdgcn_perm(u[7], u[6], 0x07060302u);
                const bf16x8 af = cv.h;
                accs1 = __builtin_amdgcn_mfma_f32_16x16x32_bf16(af, bones, accs1, 0,0,0);
                const bf16x8 b0 = *reinterpret_cast<const bf16x8*>(
                    &sm_vt[VT2_IDX(k2,1,fq,0,fr,0)]);
                const bf16x8 b1 = *reinterpret_cast<const bf16x8*>(
                    &sm_vt[VT2_IDX(k2,1,fq,1,fr,0)]);
                acc[2] = __builtin_amdgcn_mfma_f32_16x16x32_bf16(af, b0, acc[2], 0,0,0);
                acc[3] = __builtin_amdgcn_mfma_f32_16x16x32_bf16(af, b1, acc[3], 0,0,0);
            }
        }

        if (hf == 0) {
            // all waves done reading half 0; re-stage half 1 into same buffer
            __syncthreads();
#if __has_builtin(__builtin_amdgcn_global_load_lds)
            #pragma unroll
            for (int i = 0; i < 4; ++i) {
                __builtin_amdgcn_global_load_lds(
                    (const __attribute__((address_space(1))) void*)
                        (vsrc + 32768 + i*8192 + tid*16),
                    (__attribute__((address_space(3))) void*)
                        (((__attribute__((address_space(3))) char*)sm_vt) +
                         i*8192 + (tid & ~63)*16),
                    16, 0, 0);
            }
#else
            #pragma unroll
            for (int i = 0; i < 4; ++i) {
                reinterpret_cast<i32x4*>(sm_vt)[i*512 + tid] =
                    reinterpret_cast<const i32x4*>(vsrc + 32768)[i*512 + tid];
            }
#endif
            __syncthreads();
        }
    }

    // gamma/beta loaded post-loop to keep k-loop register pressure low
    const int b_  = m / NT;
    const int tt  = m % NT;
    float gmv[4], btv[4];
    #pragma unroll
    for (int dt4 = 0; dt4 < 4; ++dt4) {
        gmv[dt4] = gamma[dt4*16 + fr];
        btv[dt4] = beta [dt4*16 + fr];
    }

    // ---- epilogue: normalize + LayerNorm + store (B,C,T,N) ----
    #pragma unroll
    for (int rg = 0; rg < 4; ++rg) {
        const int rowloc = 4*fq + rg;
        const float rs0 = __shfl(accs0[rg], lane & 48);
        const float rs1 = __shfl(accs1[rg], lane & 48);
        const float inv0 = 1.f / rs0, inv1 = 1.f / rs1;
        float vv[4];
        vv[0] = acc[0][rg] * inv0;
        vv[1] = acc[1][rg] * inv0;
        vv[2] = acc[2][rg] * inv1;
        vv[3] = acc[3][rg] * inv1;
        float sum = vv[0]+vv[1]+vv[2]+vv[3];
        float ssq = vv[0]*vv[0]+vv[1]*vv[1]+vv[2]*vv[2]+vv[3]*vv[3];
        sum += __shfl_xor(sum,1); sum += __shfl_xor(sum,2);
        sum += __shfl_xor(sum,4); sum += __shfl_xor(sum,8);
        ssq += __shfl_xor(ssq,1); ssq += __shfl_xor(ssq,2);
        ssq += __shfl_xor(ssq,4); ssq += __shfl_xor(ssq,8);
        const float mu   = sum * (1.f/64.f);
        const float var  = ssq * (1.f/64.f) - mu*mu;
        const float rstd = rsqrtf(var + 1e-5f);
        const int irow = ch*128 + iloc + rowloc;
        #pragma unroll
        for (int dt4 = 0; dt4 < 4; ++dt4) {
            const float o = (vv[dt4] - mu) * rstd * gmv[dt4] + btv[dt4];
            out[((size_t)(b_*NC + dt4*16 + fr)*NT + tt)*NN + irow] = o;
        }
    }
}

// =====================================================================
// Fallback: proven single-kernel version (used only if ws too small)
// =====================================================================
__global__ __launch_bounds__(512)
void gat_fused_mono(const float* __restrict__ x, const int* __restrict__ gso,
               const float* __restrict__ Wq, const float* __restrict__ Wk,
               const float* __restrict__ Wv, const float* __restrict__ a_src,
               const float* __restrict__ a_dst, const float* __restrict__ gamma,
               const float* __restrict__ beta, float* __restrict__ out)
{
    __shared__ unsigned short sm_xrb[128][72];
    __shared__ unsigned short sm_vt[32768];
    __shared__ unsigned short sm_wvb[4096];
    __shared__ float sm_ssrc[2][NN];
    __shared__ float sm_sdst[2][NN];
    __shared__ float sm_wqa[2][NC];
    __shared__ float sm_wka[2][NC];

    const int m    = blockIdx.x;
    const int b    = m / NT;
    const int tt   = m % NT;
    const int tid  = threadIdx.x;
    const int lane = tid & 63;
    const int wid  = tid >> 6;
    const int fr   = lane & 15;
    const int fq   = lane >> 4;

    if (tid < 128) {
        const int h = tid >> 6, c = tid & 63;
        float aq = 0.f, ak = 0.f;
        #pragma unroll
        for (int d = 0; d < 32; ++d) {
            aq += Wq[(h*32 + d)*NC + c] * a_src[h*32 + d];
            ak += Wk[(h*32 + d)*NC + c] * a_dst[h*32 + d];
        }
        sm_wqa[h][c] = aq;
        sm_wka[h][c] = ak;
    }
    for (int idx = tid; idx < 4096; idx += 512) {
        const int e   = idx & 7;
        const int dl  = (idx >> 3) & 15;
        const int dt4 = (idx >> 7) & 3;
        const int qq  = (idx >> 9) & 3;
        const int ks  = idx >> 11;
        sm_wvb[idx] = f2bf(Wv[(dt4*16 + dl)*NC + ks*32 + qq*8 + e]);
    }
    __syncthreads();

    const int nl = tid >> 2;
    const int pp = tid & 3;

    for (int ch = 0; ch < 4; ++ch) {
        const int nbase = ch * 128;
        #pragma unroll
        for (int half = 0; half < 2; ++half) {
            unsigned short tmp[8];
            #pragma unroll
            for (int e = 0; e < 8; ++e) {
                const int c = pp*16 + half*8 + e;
                tmp[e] = f2bf(x[((size_t)(b*NC + c)*NT + tt)*NN + nbase + nl]);
            }
            *reinterpret_cast<bf16x8*>(&sm_xrb[nl][pp*16 + half*8]) =
                *reinterpret_cast<const bf16x8*>(tmp);
        }
        __syncthreads();
        {
            float sq0=0.f, sq1=0.f, sk0=0.f, sk1=0.f;
            #pragma unroll
            for (int cc = 0; cc < 16; ++cc) {
                const int c = pp*16 + cc;
                const float xv = bf2f(sm_xrb[nl][c]);
                sq0 += xv * sm_wqa[0][c];
                sq1 += xv * sm_wqa[1][c];
                sk0 += xv * sm_wka[0][c];
                sk1 += xv * sm_wka[1][c];
            }
            sq0 += __shfl_xor(sq0,1); sq0 += __shfl_xor(sq0,2);
            sq1 += __shfl_xor(sq1,1); sq1 += __shfl_xor(sq1,2);
            sk0 += __shfl_xor(sk0,1); sk0 += __shfl_xor(sk0,2);
            sk1 += __shfl_xor(sk1,1); sk1 += __shfl_xor(sk1,2);
            if (pp == 0) {
                sm_ssrc[0][nbase+nl] = sq0;
                sm_ssrc[1][nbase+nl] = sq1;
                sm_sdst[0][nbase+nl] = sk0;
                sm_sdst[1][nbase+nl] = sk1;
            }
        }
        {
            f32x4 vacc[4] = {};
            #pragma unroll
            for (int ks = 0; ks < 2; ++ks) {
                const bf16x8 af = *reinterpret_cast<const bf16x8*>(
                    &sm_xrb[wid*16 + fr][ks*32 + fq*8]);
                #pragma unroll
                for (int dt4 = 0; dt4 < 4; ++dt4) {
                    const bf16x8 bfv = *reinterpret_cast<const bf16x8*>(
                        &sm_wvb[(((ks*4 + fq)*4 + dt4)*16 + fr)*8]);
                    vacc[dt4] = __builtin_amdgcn_mfma_f32_16x16x32_bf16(
                        af, bfv, vacc[dt4], 0, 0, 0);
                }
            }
            #pragma unroll
            for (int dt4 = 0; dt4 < 4; ++dt4) {
                const int h = dt4 >> 1, dt = dt4 & 1;
                #pragma unroll
                for (int rg = 0; rg < 4; ++rg) {
                    const int n = nbase + wid*16 + 4*fq + rg;
                    sm_vt[VT_IDX(h, n>>5, (n>>3)&3, dt, fr, n&7)] = f2bf(vacc[dt4][rg]);
                }
            }
        }
        __syncthreads();
    }

    float gmv[4], btv[4];
    #pragma unroll
    for (int dt4 = 0; dt4 < 4; ++dt4) {
        gmv[dt4] = gamma[dt4*16 + fr];
        btv[dt4] = beta [dt4*16 + fr];
    }

    for (int it = 0; it < 4; ++it) {
        const int ibase = (wid*4 + it) * 16;
        const int ig = ibase + fr;
        const float src0 = sm_ssrc[0][ig];
        const float src1 = sm_ssrc[1][ig];
        f32x4 acc[4] = {};
        float rsum0 = 0.f, rsum1 = 0.f;

        for (int k = 0; k < 16; ++k) {
            const int j0 = k*32 + fq*8;
            const int* gp = &gso[ig*NN + j0];
            const i32x4 g0 = *reinterpret_cast<const i32x4*>(gp);
            const i32x4 g1 = *reinterpret_cast<const i32x4*>(gp + 4);
            {
                const f32x4 da = *reinterpret_cast<const f32x4*>(&sm_sdst[0][j0]);
                const f32x4 db = *reinterpret_cast<const f32x4*>(&sm_sdst[0][j0+4]);
                bf16x8 af;
                #pragma unroll
                for (int e = 0; e < 4; ++e) {
                    float sc = src0 + da[e];
                    sc = fmaxf(sc, 0.2f*sc);
                    float ev = __expf(sc);
                    ev = (g0[e] != 0) ? ev : 0.f;
                    const unsigned short wb = f2bf(ev);
                    rsum0 += bf2f(wb);
                    af[e] = (short)wb;
                }
                #pragma unroll
                for (int e = 0; e < 4; ++e) {
                    float sc = src0 + db[e];
                    sc = fmaxf(sc, 0.2f*sc);
                    float ev = __expf(sc);
                    ev = (g1[e] != 0) ? ev : 0.f;
                    const unsigned short wb = f2bf(ev);
                    rsum0 += bf2f(wb);
                    af[4+e] = (short)wb;
                }
                const bf16x8 b0 = *reinterpret_cast<const bf16x8*>(&sm_vt[VT_IDX(0,k,fq,0,fr,0)]);
                const bf16x8 b1 = *reinterpret_cast<const bf16x8*>(&sm_vt[VT_IDX(0,k,fq,1,fr,0)]);
                acc[0] = __builtin_amdgcn_mfma_f32_16x16x32_bf16(af, b0, acc[0], 0,0,0);
                acc[1] = __builtin_amdgcn_mfma_f32_16x16x32_bf16(af, b1, acc[1], 0,0,0);
            }
            {
                const f32x4 da = *reinterpret_cast<const f32x4*>(&sm_sdst[1][j0]);
                const f32x4 db = *reinterpret_cast<const f32x4*>(&sm_sdst[1][j0+4]);
                bf16x8 af;
                #pragma unroll
                for (int e = 0; e < 4; ++e) {
                    float sc = src1 + da[e];
                    sc = fmaxf(sc, 0.2f*sc);
                    float ev = __expf(sc);
                    ev = (g0[e] != 0) ? ev : 0.f;
                    const unsigned short wb = f2bf(ev);
                    rsum1 += bf2f(wb);
                    af[e] = (short)wb;
                }
                #pragma unroll
                for (int e = 0; e < 4; ++e) {
                    float sc = src1 + db[e];
                    sc = fmaxf(sc, 0.2f*sc);
                    float ev = __expf(sc);
                    ev = (g1[e] != 0) ? ev : 0.f;
                    const unsigned short wb = f2bf(ev);
                    rsum1 += bf2f(wb);
                    af[4+e] = (short)wb;
                }
                const bf16x8 b0 = *reinterpret_cast<const bf16x8*>(&sm_vt[VT_IDX(1,k,fq,0,fr,0)]);
                const bf16x8 b1 = *reinterpret_cast<const bf16x8*>(&sm_vt[VT_IDX(1,k,fq,1,fr,0)]);
                acc[2] = __builtin_amdgcn_mfma_f32_16x16x32_bf16(af, b0, acc[2], 0,0,0);
                acc[3] = __builtin_amdgcn_mfma_f32_16x16x32_bf16(af, b1, acc[3], 0,0,0);
            }
        }

        rsum0 += __shfl_xor(rsum0, 16); rsum0 += __shfl_xor(rsum0, 32);
        rsum1 += __shfl_xor(rsum1, 16); rsum1 += __shfl_xor(rsum1, 32);

        #pragma unroll
        for (int rg = 0; rg < 4; ++rg) {
            const int rowloc   = 4*fq + rg;
            const int src_lane = (lane & 48) | rowloc;
            const float rs0 = __shfl(rsum0, src_lane);
            const float rs1 = __shfl(rsum1, src_lane);
            const float inv0 = 1.f / rs0, inv1 = 1.f / rs1;
            float vv[4];
            vv[0] = acc[0][rg] * inv0;
            vv[1] = acc[1][rg] * inv0;
            vv[2] = acc[2][rg] * inv1;
            vv[3] = acc[3][rg] * inv1;
            float sum = vv[0]+vv[1]+vv[2]+vv[3];
            float ssq = vv[0]*vv[0]+vv[1]*vv[1]+vv[2]*vv[2]+vv[3]*vv[3];
            sum += __shfl_xor(sum,1); sum += __shfl_xor(sum,2);
            sum += __shfl_xor(sum,4); sum += __shfl_xor(sum,8);
            ssq += __shfl_xor(ssq,1); ssq += __shfl_xor(ssq,2);
            ssq += __shfl_xor(ssq,4); ssq += __shfl_xor(ssq,8);
            const float mu   = sum * (1.f/64.f);
            const float var  = ssq * (1.f/64.f) - mu*mu;
            const float rstd = rsqrtf(var + 1e-5f);
            const int irow = ibase + rowloc;
            #pragma unroll
            for (int dt4 = 0; dt4 < 4; ++dt4) {
                const float o = (vv[dt4] - mu) * rstd * gmv[dt4] + btv[dt4];
                out[((size_t)(b*NC + dt4*16 + fr)*NT + tt)*NN + irow] = o;
            }
        }
    }
}

extern "C" void kernel_launch(void* const* d_in, const int* in_sizes, int n_in,
                              void* d_out, int out_size, void* d_ws, size_t ws_size,
                              hipStream_t stream) {
    (void)in_sizes; (void)n_in; (void)out_size;
    const float* x     = (const float*)d_in[0];
    const int*   gso   = (const int*)  d_in[1];
    const float* Wq    = (const float*)d_in[2];
    const float* Wk    = (const float*)d_in[3];
    const float* Wv    = (const float*)d_in[4];
    const float* a_src = (const float*)d_in[5];
    const float* a_dst = (const float*)d_in[6];
    const float* gamma = (const float*)d_in[7];
    const float* beta  = (const float*)d_in[8];
    float* out = (float*)d_out;

    if (ws_size >= (size_t)WS_NEEDED && d_ws != nullptr) {
        unsigned short* vt = (unsigned short*)((char*)d_ws + WS_VT_OFF);
        float* ssrc  = (float*)((char*)d_ws + WS_SSRC_OFF);
        float* sdst  = (float*)((char*)d_ws + WS_SDST_OFF);
        gat_proj<<<768, 512, 0, stream>>>(x, Wq, Wk, Wv, a_src, a_dst,
                                          vt, ssrc, sdst);
        gat_attn<<<768, 512, 0, stream>>>(vt, ssrc, sdst, gso,
                                          gamma, beta, out);
    } else {
        gat_fused_mono<<<NM, 512, 0, stream>>>(x, gso, Wq, Wk, Wv, a_src, a_dst,
                                               gamma, beta, out);
    }
}